// Round 6
// baseline (123.009 us; speedup 1.0000x reference)
//
#include <hip/hip_runtime.h>

#ifndef __has_builtin
#define __has_builtin(x) 0
#endif
#if __has_builtin(__builtin_amdgcn_exp2f)
#define EXP2F(x) __builtin_amdgcn_exp2f(x)
#else
#define EXP2F(x) exp2f(x)
#endif

namespace {

constexpr int T = 4096;
constexpr int C = 128;
constexpr int H = 8;
constexpr int D = 16;
constexpr int BH = 16;                         // B*H
constexpr size_t PLANE = (size_t)BH * T * D;   // 1,048,576 elements per tensor
constexpr size_t BHT = (size_t)BH * T;         // 65,536 rows

using bf16x8 = __attribute__((ext_vector_type(8))) short;
using u16x4  = __attribute__((ext_vector_type(4))) unsigned short;
using f32x16 = __attribute__((ext_vector_type(16))) float;

__device__ __forceinline__ uint32_t cvt_pk_bf16(float lo, float hi) {
  uint32_t r;
  asm volatile("v_cvt_pk_bf16_f32 %0, %1, %2" : "=v"(r) : "v"(lo), "v"(hi));
  return r;
}

// ---------------------------------------------------------------------------
// Kernel 1: QKV projection -> bf16 (coalesced stores via LDS repack).
//   Qbf[bh][t][d] (pre-scaled by D^-1/2*log2e), Kbf[bh][t][d], Vt[bh][d][t].
// ---------------------------------------------------------------------------
__global__ __launch_bounds__(256) void qkv_proj(
    const float* __restrict__ x, const float* __restrict__ Wq,
    const float* __restrict__ Wk, const float* __restrict__ Wv,
    unsigned short* __restrict__ Qbf, unsigned short* __restrict__ Kbf,
    unsigned short* __restrict__ Vt) {
  __shared__ float Xs[128][68];  // [k][m]
  __shared__ float Ws[128][68];  // [k][n]
  const int tid = threadIdx.x;
  const int bm = blockIdx.x;            // 128 row blocks
  const int bn = blockIdx.y;            // 6 col blocks
  const int mat = bn >> 1;              // 0=Q 1=K 2=V
  const int c0 = (bn & 1) * 64;
  const float* W = (mat == 0) ? Wq : (mat == 1) ? Wk : Wv;
  const int t0 = bm * 64;

  const float4* xsrc = (const float4*)(x + (size_t)t0 * C);
  const float4* wsrc = (const float4*)(W + (size_t)c0 * C);
  for (int f = tid; f < 2048; f += 256) {
    const int m = f >> 5, k = (f & 31) << 2;
    float4 v = xsrc[f];
    Xs[k + 0][m] = v.x; Xs[k + 1][m] = v.y; Xs[k + 2][m] = v.z; Xs[k + 3][m] = v.w;
    float4 u = wsrc[f];
    Ws[k + 0][m] = u.x; Ws[k + 1][m] = u.y; Ws[k + 2][m] = u.z; Ws[k + 3][m] = u.w;
  }
  __syncthreads();

  const int tx = tid & 15, ty = tid >> 4;
  float acc[4][4] = {};
#pragma unroll 8
  for (int k = 0; k < 128; ++k) {
    const float4 a = *(const float4*)&Xs[k][ty * 4];
    const float4 b = *(const float4*)&Ws[k][tx * 4];
    const float av[4] = {a.x, a.y, a.z, a.w};
    const float bv[4] = {b.x, b.y, b.z, b.w};
#pragma unroll
    for (int i = 0; i < 4; ++i)
#pragma unroll
      for (int j = 0; j < 4; ++j) acc[i][j] = fmaf(av[i], bv[j], acc[i][j]);
  }
  __syncthreads();  // done reading Xs -> reuse as bf16 staging

  unsigned short* Ls = (unsigned short*)&Xs[0][0];  // [64][72] bf16
  if (mat < 2) {
    const float sc = (mat == 0) ? 0.25f * 1.4426950408889634f : 1.0f;
#pragma unroll
    for (int i = 0; i < 4; ++i) {                 // Ls[t][c] packed bf16
      const uint32_t u0 = cvt_pk_bf16(acc[i][0] * sc, acc[i][1] * sc);
      const uint32_t u1 = cvt_pk_bf16(acc[i][2] * sc, acc[i][3] * sc);
      *(uint32_t*)&Ls[(ty * 4 + i) * 72 + tx * 4]     = u0;
      *(uint32_t*)&Ls[(ty * 4 + i) * 72 + tx * 4 + 2] = u1;
    }
    __syncthreads();
    unsigned short* dst = (mat == 0) ? Qbf : Kbf;
    const int lane = tid & 63, hp = tid >> 6;     // wave hp -> head-slot hp
    const int tr = t0 + lane, b = tr >> 12, t = tr & (T - 1);
    const int head = (c0 >> 4) + hp;
    unsigned short* base = dst + (((size_t)(b * H + head)) * T + t) * D;
#pragma unroll
    for (int p = 0; p < 2; ++p)                   // 2x16B per lane, coalesced
      *(uint4*)(base + p * 8) = *(const uint4*)&Ls[lane * 72 + hp * 16 + p * 8];
  } else {
#pragma unroll
    for (int j = 0; j < 4; ++j) {                 // Ls[c][t] (transposed)
      const uint32_t u0 = cvt_pk_bf16(acc[0][j], acc[1][j]);
      const uint32_t u1 = cvt_pk_bf16(acc[2][j], acc[3][j]);
      *(uint32_t*)&Ls[(tx * 4 + j) * 72 + ty * 4]     = u0;
      *(uint32_t*)&Ls[(tx * 4 + j) * 72 + ty * 4 + 2] = u1;
    }
    __syncthreads();
    const int c = tid >> 2;                       // 0..63
    const int b = t0 >> 12;
    const int head = (c0 + c) >> 4, dvv = (c0 + c) & 15;
    unsigned short* base =
        Vt + (((size_t)(b * H + head)) * D + dvv) * T + (t0 & (T - 1));
#pragma unroll
    for (int it = 0; it < 2; ++it) {
      const int part = (tid & 3) + 4 * it;
      *(uint4*)(base + part * 8) = *(const uint4*)&Ls[c * 72 + part * 8];
    }
  }
}

// ---------------------------------------------------------------------------
// Kernel 2a: causal flash attention partials, 32x32x16 bf16 MFMA.
// Pair (127-j, j) = 129 key-steps -> 8-way split: 2 blocks x 4 waves; global
// slot = half*4+w takes combined steps i == slot (mod 8).  Grid = 2048 equal
// blocks = 8 blocks/CU = 32 waves/CU (100% cap).  LDS 19.5KB*8 = 155.6KB,
// launch_bounds(256,8) caps VGPR at 64 (round-5 body was 60 -> no spill).
// Each block merges its 4 waves in LDS and writes UNNORMALIZED partials
// (M, L, O) for its half to ws; kernel 2b combines the two halves.
// ---------------------------------------------------------------------------
__global__ __launch_bounds__(256, 8) void attn_partial(
    const unsigned short* __restrict__ Qbf, const unsigned short* __restrict__ Kbf,
    const unsigned short* __restrict__ Vt, float* __restrict__ Og,
    float* __restrict__ Mg, float* __restrict__ Lg) {
  __shared__ float Pm[2][4][32];
  __shared__ float Pl[2][4][32];
  __shared__ float Po[2][4][32][17];
  const int tid = threadIdx.x;
  const int w = tid >> 6, l = tid & 63;
  const int lane31 = l & 31, h = l >> 5, dv = l & 15;
  const int ib = blockIdx.x;
  const int bh = 2 * (ib & 7) + ((ib >> 3) & 1);  // XCD x <- bh {2x, 2x+1}
  const int half = (ib >> 4) & 1;
  const int pj = ib >> 5;                         // 0..63
  const int tileA = 127 - pj, tileB = pj;
  const int nsA = tileA + 1, nsB = tileB + 1;     // nsA >= 65 > 8 always
  const int slot = half * 4 + w;                  // 0..7

  const unsigned short* Qp = Qbf + (size_t)bh * T * D;
  const unsigned short* Kp = Kbf + (size_t)bh * T * D;
  const unsigned short* Vp = Vt + (size_t)bh * D * T;

  auto run_phase = [&](int tile, int s0, int ns, int phase) {
    const int qidx = tile * 32 + lane31;
    const bf16x8 qf = *(const bf16x8*)(Qp + (size_t)qidx * D + 8 * h);
    float m = -1e30f, lsum = 0.f;       // first check always rescales (a=0)
    f32x16 acc = {};
#pragma unroll 1
    for (int s = s0; s < ns; s += 8) {
      const int k0 = s * 32;
      const bf16x8 kf = *(const bf16x8*)(Kp + (size_t)(k0 + lane31) * D + 8 * h);
      const unsigned short* vb = Vp + (size_t)dv * T + k0 + 4 * h;
      const u16x4 v0 = *(const u16x4*)(vb);
      const u16x4 v1 = *(const u16x4*)(vb + 8);
      const u16x4 v2 = *(const u16x4*)(vb + 16);
      const u16x4 v3 = *(const u16x4*)(vb + 24);

      f32x16 s16 = {};
      __builtin_amdgcn_s_setprio(1);
      s16 = __builtin_amdgcn_mfma_f32_32x32x16_bf16(kf, qf, s16, 0, 0, 0);
      __builtin_amdgcn_s_setprio(0);

      if (s == tile) {                  // diagonal step: causal mask
#pragma unroll
        for (int r = 0; r < 16; ++r) {
          const int key = k0 + (r & 3) + 8 * (r >> 2) + 4 * h;
          if (key > qidx) s16[r] = -1e30f;
        }
      }

      const float t0 = fmaxf(fmaxf(s16[0], s16[1]), s16[2]);
      const float t1 = fmaxf(fmaxf(s16[3], s16[4]), s16[5]);
      const float t2 = fmaxf(fmaxf(s16[6], s16[7]), s16[8]);
      const float t3 = fmaxf(fmaxf(s16[9], s16[10]), s16[11]);
      const float t4 = fmaxf(fmaxf(s16[12], s16[13]), s16[14]);
      const float lm =
          fmaxf(fmaxf(fmaxf(t0, t1), t2), fmaxf(fmaxf(t3, t4), s16[15]));

      if (!__all(lm <= m + 8.f)) {      // rare (deferred max), wave-uniform
        const float tm = fmaxf(lm, __shfl_xor(lm, 32, 64));
        const float mn = fmaxf(m, tm);
        const float alpha = EXP2F(m - mn);
        lsum *= alpha;
#pragma unroll
        for (int j = 0; j < 8; ++j) acc[j] *= alpha;
        m = mn;
      }

#pragma unroll
      for (int r = 0; r < 16; ++r) s16[r] = EXP2F(s16[r] - m);
      lsum += ((s16[0] + s16[1]) + (s16[2] + s16[3])) +
              ((s16[4] + s16[5]) + (s16[6] + s16[7])) +
              ((s16[8] + s16[9]) + (s16[10] + s16[11])) +
              ((s16[12] + s16[13]) + (s16[14] + s16[15]));

      union PF { bf16x8 v; uint32_t u[4]; } pa, pb;
      pa.u[0] = cvt_pk_bf16(s16[0], s16[1]);
      pa.u[1] = cvt_pk_bf16(s16[2], s16[3]);
      pa.u[2] = cvt_pk_bf16(s16[4], s16[5]);
      pa.u[3] = cvt_pk_bf16(s16[6], s16[7]);
      pb.u[0] = cvt_pk_bf16(s16[8], s16[9]);
      pb.u[1] = cvt_pk_bf16(s16[10], s16[11]);
      pb.u[2] = cvt_pk_bf16(s16[12], s16[13]);
      pb.u[3] = cvt_pk_bf16(s16[14], s16[15]);

      union VF { bf16x8 v; u16x4 q4[2]; } va, vbu;
      va.q4[0] = v0;  va.q4[1] = v1;    // keys k0+0..15  (slot fn = P's)
      vbu.q4[0] = v2; vbu.q4[1] = v3;   // keys k0+16..31
      __builtin_amdgcn_s_setprio(1);
      acc = __builtin_amdgcn_mfma_f32_32x32x16_bf16(va.v, pa.v, acc, 0, 0, 0);
      acc = __builtin_amdgcn_mfma_f32_32x32x16_bf16(vbu.v, pb.v, acc, 0, 0, 0);
      __builtin_amdgcn_s_setprio(0);
    }
    lsum += __shfl_xor(lsum, 32, 64);   // lane pair holds same q
    Pm[phase][w][lane31] = m;
    Pl[phase][w][lane31] = lsum;
#pragma unroll
    for (int j = 0; j < 8; ++j) {
      const int dj = (j & 3) + 8 * (j >> 2) + 4 * h;
      Po[phase][w][lane31][dj] = acc[j];
    }
  };

  // phase A: combined steps i = slot, slot+8, ... while i < nsA
  run_phase(tileA, slot, nsA, 0);
  // phase B: continue the combined list past nsA
  const int cA = (nsA - slot + 7) >> 3;
  const int sB0 = slot + 8 * cA - nsA;
  run_phase(tileB, sB0, nsB, 1);

  __syncthreads();

  if (w < 2) {                          // wave 0 -> tile A, wave 1 -> tile B
    const int tile = (w == 0) ? tileA : tileB;
    const int qidx = tile * 32 + lane31;
    float M = Pm[w][0][lane31];
#pragma unroll
    for (int p = 1; p < 4; ++p) M = fmaxf(M, Pm[w][p][lane31]);
    float L = 0.f, od[8] = {};
#pragma unroll
    for (int p = 0; p < 4; ++p) {
      const float wsc = EXP2F(Pm[w][p][lane31] - M);  // empty slots -> 0
      L = fmaf(Pl[w][p][lane31], wsc, L);
#pragma unroll
      for (int j = 0; j < 8; ++j) {
        const int dj = (j & 3) + 8 * (j >> 2) + 4 * h;
        od[j] = fmaf(Po[w][p][lane31][dj], wsc, od[j]);
      }
    }
    // write UNNORMALIZED partial for this half
    const size_t row = (size_t)bh * T + qidx;
    float* base = Og + ((size_t)half * PLANE) + row * D;
    *(float4*)(base + 4 * h)     = make_float4(od[0], od[1], od[2], od[3]);
    *(float4*)(base + 8 + 4 * h) = make_float4(od[4], od[5], od[6], od[7]);
    if (h == 0) {
      Mg[half * BHT + row] = M;
      Lg[half * BHT + row] = L;
    }
  }
}

// ---------------------------------------------------------------------------
// Kernel 2b: combine the two halves' partials into att (in place over half-0
// O plane; element-wise, each thread reads its own slot then writes it).
// ---------------------------------------------------------------------------
__global__ __launch_bounds__(256) void attn_merge(
    float* __restrict__ Og, const float* __restrict__ Mg,
    const float* __restrict__ Lg) {
  const int e = blockIdx.x * 256 + threadIdx.x;   // < BHT*4
  const size_t row = (size_t)(e >> 2);
  const int dp = (e & 3) << 2;
  const float m0 = Mg[row], m1 = Mg[BHT + row];
  const float l0 = Lg[row], l1 = Lg[BHT + row];
  const float M = fmaxf(m0, m1);
  const float e0 = EXP2F(m0 - M), e1 = EXP2F(m1 - M);
  const float inv = 1.f / fmaf(e0, l0, e1 * l1);
  const float4 o0 = *(const float4*)(Og + row * D + dp);
  const float4 o1 = *(const float4*)(Og + PLANE + row * D + dp);
  *(float4*)(Og + row * D + dp) =
      make_float4((o0.x * e0 + o1.x * e1) * inv, (o0.y * e0 + o1.y * e1) * inv,
                  (o0.z * e0 + o1.z * e1) * inv, (o0.w * e0 + o1.w * e1) * inv);
}

// ---------------------------------------------------------------------------
// Kernel 3: output projection + bias (fp32, unchanged).
// ---------------------------------------------------------------------------
__global__ __launch_bounds__(256) void out_proj(
    const float* __restrict__ att, const float* __restrict__ Wp,
    const float* __restrict__ bp, float* __restrict__ out) {
  __shared__ float As[128][68];
  __shared__ float Bs[128][68];
  const int tid = threadIdx.x;
  const int t0 = blockIdx.x * 64;
  const int c0 = blockIdx.y * 64;

  for (int f = tid; f < 2048; f += 256) {
    const int mm = f & 63;
    const int cp = (f >> 6) << 2;
    const int tr = t0 + mm;
    const int b = tr >> 12, t = tr & (T - 1);
    const int h = cp >> 4, d0 = cp & 15;
    const float4 v = *(const float4*)(att + (((size_t)b * H + h) * T + t) * D + d0);
    As[cp + 0][mm] = v.x; As[cp + 1][mm] = v.y; As[cp + 2][mm] = v.z; As[cp + 3][mm] = v.w;
  }
  const float4* wsrc = (const float4*)(Wp + (size_t)c0 * C);
  for (int f = tid; f < 2048; f += 256) {
    const float4 v = wsrc[f];
    const int n = f >> 5, k = (f & 31) << 2;
    Bs[k + 0][n] = v.x; Bs[k + 1][n] = v.y; Bs[k + 2][n] = v.z; Bs[k + 3][n] = v.w;
  }
  __syncthreads();

  const int tx = tid & 15, ty = tid >> 4;
  float acc[4][4] = {};
#pragma unroll 8
  for (int k = 0; k < 128; ++k) {
    const float4 a = *(const float4*)&As[k][ty * 4];
    const float4 b = *(const float4*)&Bs[k][tx * 4];
    const float av[4] = {a.x, a.y, a.z, a.w};
    const float bv[4] = {b.x, b.y, b.z, b.w};
#pragma unroll
    for (int i = 0; i < 4; ++i)
#pragma unroll
      for (int j = 0; j < 4; ++j) acc[i][j] = fmaf(av[i], bv[j], acc[i][j]);
  }

  const float4 bias = *(const float4*)(bp + c0 + tx * 4);
#pragma unroll
  for (int i = 0; i < 4; ++i) {
    const int tr = t0 + ty * 4 + i;
    const float4 v = make_float4(acc[i][0] + bias.x, acc[i][1] + bias.y,
                                 acc[i][2] + bias.z, acc[i][3] + bias.w);
    *(float4*)(out + (size_t)tr * C + c0 + tx * 4) = v;
  }
}

}  // namespace

extern "C" void kernel_launch(void* const* d_in, const int* in_sizes, int n_in,
                              void* d_out, int out_size, void* d_ws, size_t ws_size,
                              hipStream_t stream) {
  // setup_inputs order: x, Wk, Wq, Wv, Wp, bp
  const float* x  = (const float*)d_in[0];
  const float* Wk = (const float*)d_in[1];
  const float* Wq = (const float*)d_in[2];
  const float* Wv = (const float*)d_in[3];
  const float* Wp = (const float*)d_in[4];
  const float* bp = (const float*)d_in[5];

  float* wsf = (float*)d_ws;
  float* Og = wsf;                            // [2][BH][T][D]  8 MiB
  float* Mg = wsf + 2 * PLANE;                // [2][BH*T]      512 KiB
  float* Lg = Mg + 2 * BHT;                   // [2][BH*T]      512 KiB
  unsigned short* Qbf = (unsigned short*)(Lg + 2 * BHT);  // 2 MiB bf16
  unsigned short* Kbf = Qbf + PLANE;          // 2 MiB
  unsigned short* Vtb = Kbf + PLANE;          // 2 MiB   (total 15.0 MiB)

  qkv_proj<<<dim3(128, 6), 256, 0, stream>>>(x, Wq, Wk, Wv, Qbf, Kbf, Vtb);
  attn_partial<<<dim3(2048), 256, 0, stream>>>(Qbf, Kbf, Vtb, Og, Mg, Lg);
  attn_merge<<<dim3(1024), 256, 0, stream>>>(Og, Mg, Lg);
  out_proj<<<dim3(128, 2), 256, 0, stream>>>(Og /* = att */, Wp, bp,
                                             (float*)d_out);
}

// Round 7
// 76.381 us; speedup vs baseline: 1.6105x; 1.6105x over previous
//
#include <hip/hip_runtime.h>

#ifndef __has_builtin
#define __has_builtin(x) 0
#endif
#if __has_builtin(__builtin_amdgcn_exp2f)
#define EXP2F(x) __builtin_amdgcn_exp2f(x)
#else
#define EXP2F(x) exp2f(x)
#endif

namespace {

constexpr int T = 4096;
constexpr int C = 128;
constexpr int H = 8;
constexpr int D = 16;
constexpr int BH = 16;                         // B*H
constexpr size_t PLANE = (size_t)BH * T * D;   // 1,048,576 elements per tensor
constexpr int NTILE = T / 32;                  // 128 key-tiles per bh

using bf16x8 = __attribute__((ext_vector_type(8))) short;
using u16x4  = __attribute__((ext_vector_type(4))) unsigned short;
using f32x16 = __attribute__((ext_vector_type(16))) float;

__device__ __forceinline__ uint32_t cvt_pk_bf16(float lo, float hi) {
  uint32_t r;
  asm volatile("v_cvt_pk_bf16_f32 %0, %1, %2" : "=v"(r) : "v"(lo), "v"(hi));
  return r;
}

// ---------------------------------------------------------------------------
// Kernel 1: QKV projection -> bf16 (coalesced stores via LDS repack).
//   Qbf[bh][t][d] (pre-scaled by D^-1/2*log2e), Kbf[bh][t][d],
//   Vt TILED: [bh][t/32][d=16][k=32] -- 1KB contiguous block per 32-key tile.
//   (Old [bh][d][T] layout gathered/wrote 64B chunks at 8KB stride -> L2
//   channel camping; the cross-round ~70us attn floor and the qkv tail.)
// ---------------------------------------------------------------------------
__global__ __launch_bounds__(256) void qkv_proj(
    const float* __restrict__ x, const float* __restrict__ Wq,
    const float* __restrict__ Wk, const float* __restrict__ Wv,
    unsigned short* __restrict__ Qbf, unsigned short* __restrict__ Kbf,
    unsigned short* __restrict__ Vt) {
  __shared__ float Xs[128][68];  // [k][m]
  __shared__ float Ws[128][68];  // [k][n]
  const int tid = threadIdx.x;
  const int bm = blockIdx.x;            // 128 row blocks
  const int bn = blockIdx.y;            // 6 col blocks
  const int mat = bn >> 1;              // 0=Q 1=K 2=V
  const int c0 = (bn & 1) * 64;
  const float* W = (mat == 0) ? Wq : (mat == 1) ? Wk : Wv;
  const int t0 = bm * 64;

  const float4* xsrc = (const float4*)(x + (size_t)t0 * C);
  const float4* wsrc = (const float4*)(W + (size_t)c0 * C);
  for (int f = tid; f < 2048; f += 256) {
    const int m = f >> 5, k = (f & 31) << 2;
    float4 v = xsrc[f];
    Xs[k + 0][m] = v.x; Xs[k + 1][m] = v.y; Xs[k + 2][m] = v.z; Xs[k + 3][m] = v.w;
    float4 u = wsrc[f];
    Ws[k + 0][m] = u.x; Ws[k + 1][m] = u.y; Ws[k + 2][m] = u.z; Ws[k + 3][m] = u.w;
  }
  __syncthreads();

  const int tx = tid & 15, ty = tid >> 4;
  float acc[4][4] = {};
#pragma unroll 8
  for (int k = 0; k < 128; ++k) {
    const float4 a = *(const float4*)&Xs[k][ty * 4];
    const float4 b = *(const float4*)&Ws[k][tx * 4];
    const float av[4] = {a.x, a.y, a.z, a.w};
    const float bv[4] = {b.x, b.y, b.z, b.w};
#pragma unroll
    for (int i = 0; i < 4; ++i)
#pragma unroll
      for (int j = 0; j < 4; ++j) acc[i][j] = fmaf(av[i], bv[j], acc[i][j]);
  }
  __syncthreads();  // done reading Xs -> reuse as bf16 staging

  unsigned short* Ls = (unsigned short*)&Xs[0][0];  // [64][72] bf16
  if (mat < 2) {
    const float sc = (mat == 0) ? 0.25f * 1.4426950408889634f : 1.0f;
#pragma unroll
    for (int i = 0; i < 4; ++i) {                 // Ls[t][c] packed bf16
      const uint32_t u0 = cvt_pk_bf16(acc[i][0] * sc, acc[i][1] * sc);
      const uint32_t u1 = cvt_pk_bf16(acc[i][2] * sc, acc[i][3] * sc);
      *(uint32_t*)&Ls[(ty * 4 + i) * 72 + tx * 4]     = u0;
      *(uint32_t*)&Ls[(ty * 4 + i) * 72 + tx * 4 + 2] = u1;
    }
    __syncthreads();
    unsigned short* dst = (mat == 0) ? Qbf : Kbf;
    const int lane = tid & 63, hp = tid >> 6;     // wave hp -> head-slot hp
    const int tr = t0 + lane, b = tr >> 12, t = tr & (T - 1);
    const int head = (c0 >> 4) + hp;
    unsigned short* base = dst + (((size_t)(b * H + head)) * T + t) * D;
#pragma unroll
    for (int p = 0; p < 2; ++p)                   // 2x16B per lane, coalesced
      *(uint4*)(base + p * 8) = *(const uint4*)&Ls[lane * 72 + hp * 16 + p * 8];
  } else {
#pragma unroll
    for (int j = 0; j < 4; ++j) {                 // Ls[c][t] (transposed)
      const uint32_t u0 = cvt_pk_bf16(acc[0][j], acc[1][j]);
      const uint32_t u1 = cvt_pk_bf16(acc[2][j], acc[3][j]);
      *(uint32_t*)&Ls[(tx * 4 + j) * 72 + ty * 4]     = u0;
      *(uint32_t*)&Ls[(tx * 4 + j) * 72 + ty * 4 + 2] = u1;
    }
    __syncthreads();
    const int c = tid >> 2;                       // 0..63
    const int b = t0 >> 12;
    const int head = (c0 + c) >> 4, dvv = (c0 + c) & 15;
    const int tile0 = (t0 & (T - 1)) >> 5;        // t0 is 64-aligned
    unsigned short* vbase =
        Vt + (((size_t)(b * H + head) * NTILE + tile0) * D + dvv) * 32;
#pragma unroll
    for (int it = 0; it < 2; ++it) {
      const int part = (tid & 3) + 4 * it;        // 0..7
      // tile (part>>2), within-tile col (part&3)*8 -- 1KB/wave contiguous
      *(uint4*)(vbase + (part >> 2) * (D * 32) + (part & 3) * 8) =
          *(const uint4*)&Ls[c * 72 + part * 8];
    }
  }
}

// ---------------------------------------------------------------------------
// Kernel 2: causal flash attention, 32x32x16 bf16 MFMA, paired-tile blocks.
// Round-5 structure (proven 60 VGPR, no spills): block = 4 waves owning pair
// (127-j, j) = 129 steps, wave w takes steps i == w (mod 4), 2-step unroll,
// in-block LDS merge.  ONLY change: V reads now hit the tiled Vt layout --
// per step the 4 loads touch 16 consecutive lines in one 1KB block (L1-
// resident) instead of 16 lines at 8KB stride (channel camping).
// ---------------------------------------------------------------------------
__global__ __launch_bounds__(256, 4) void attn_fwd(
    const unsigned short* __restrict__ Qbf, const unsigned short* __restrict__ Kbf,
    const unsigned short* __restrict__ Vt, float* __restrict__ att) {
  __shared__ float Pm[2][4][32];
  __shared__ float Pl[2][4][32];
  __shared__ float Po[2][4][32][17];
  const int tid = threadIdx.x;
  const int w = tid >> 6, l = tid & 63;
  const int lane31 = l & 31, h = l >> 5, dv = l & 15;
  const int ib = blockIdx.x;
  const int bh = 2 * (ib & 7) + ((ib >> 3) & 1);  // XCD x <- bh {2x, 2x+1}
  const int pj = ib >> 4;                         // 0..63
  const int tileA = 127 - pj, tileB = pj;
  const int nsA = tileA + 1, nsB = tileB + 1;     // nsA >= 65 > 4 always

  const unsigned short* Qp = Qbf + (size_t)bh * T * D;
  const unsigned short* Kp = Kbf + (size_t)bh * T * D;
  const unsigned short* Vp = Vt + (size_t)bh * T * D;   // tiled plane

  auto run_phase = [&](int tile, int s0, int ns, int slot) {
    const int qidx = tile * 32 + lane31;
    const bf16x8 qf = *(const bf16x8*)(Qp + (size_t)qidx * D + 8 * h);
    float m = -1e30f, lsum = 0.f;       // first check always rescales (a=0)
    f32x16 acc = {};

    auto loadK = [&](int s) -> bf16x8 {
      return *(const bf16x8*)(Kp + (size_t)(s * 32 + lane31) * D + 8 * h);
    };
    auto vtile = [&](int s) -> const unsigned short* {
      return Vp + ((size_t)s * D + dv) * 32 + 4 * h;
    };
    auto mask_diag = [&](f32x16& s16, int k0) {
#pragma unroll
      for (int r = 0; r < 16; ++r) {
        const int key = k0 + (r & 3) + 8 * (r >> 2) + 4 * h;
        if (key > qidx) s16[r] = -1e30f;
      }
    };
    auto lmax16 = [&](const f32x16& s16) -> float {
      const float t0 = fmaxf(fmaxf(s16[0], s16[1]), s16[2]);
      const float t1 = fmaxf(fmaxf(s16[3], s16[4]), s16[5]);
      const float t2 = fmaxf(fmaxf(s16[6], s16[7]), s16[8]);
      const float t3 = fmaxf(fmaxf(s16[9], s16[10]), s16[11]);
      const float t4 = fmaxf(fmaxf(s16[12], s16[13]), s16[14]);
      return fmaxf(fmaxf(fmaxf(t0, t1), t2), fmaxf(fmaxf(t3, t4), s16[15]));
    };
    auto rescale_if = [&](float lm) {
      if (!__all(lm <= m + 8.f)) {      // rare (deferred max), wave-uniform
        const float tm = fmaxf(lm, __shfl_xor(lm, 32, 64));
        const float mn = fmaxf(m, tm);
        const float alpha = EXP2F(m - mn);
        lsum *= alpha;
#pragma unroll
        for (int j = 0; j < 8; ++j) acc[j] *= alpha;
        m = mn;
      }
    };
    auto expsum = [&](f32x16& s16) {
#pragma unroll
      for (int r = 0; r < 16; ++r) s16[r] = EXP2F(s16[r] - m);
      lsum += ((s16[0] + s16[1]) + (s16[2] + s16[3])) +
              ((s16[4] + s16[5]) + (s16[6] + s16[7])) +
              ((s16[8] + s16[9]) + (s16[10] + s16[11])) +
              ((s16[12] + s16[13]) + (s16[14] + s16[15]));
    };
    auto pv = [&](const f32x16& s16, const u16x4& v0, const u16x4& v1,
                  const u16x4& v2, const u16x4& v3) {
      union PF { bf16x8 v; uint32_t u[4]; } pa, pb;
      pa.u[0] = cvt_pk_bf16(s16[0], s16[1]);
      pa.u[1] = cvt_pk_bf16(s16[2], s16[3]);
      pa.u[2] = cvt_pk_bf16(s16[4], s16[5]);
      pa.u[3] = cvt_pk_bf16(s16[6], s16[7]);
      pb.u[0] = cvt_pk_bf16(s16[8], s16[9]);
      pb.u[1] = cvt_pk_bf16(s16[10], s16[11]);
      pb.u[2] = cvt_pk_bf16(s16[12], s16[13]);
      pb.u[3] = cvt_pk_bf16(s16[14], s16[15]);
      union VF { bf16x8 v; u16x4 q4[2]; } va, vb;
      va.q4[0] = v0; va.q4[1] = v1;     // keys k0+0..15  (slot fn = P's)
      vb.q4[0] = v2; vb.q4[1] = v3;     // keys k0+16..31
      __builtin_amdgcn_s_setprio(1);
      acc = __builtin_amdgcn_mfma_f32_32x32x16_bf16(va.v, pa.v, acc, 0, 0, 0);
      acc = __builtin_amdgcn_mfma_f32_32x32x16_bf16(vb.v, pb.v, acc, 0, 0, 0);
      __builtin_amdgcn_s_setprio(0);
    };

    int s = s0;
#pragma unroll 1
    for (; s + 4 < ns; s += 8) {        // two steps per iter: s and s+4
      const unsigned short* vba = vtile(s);
      const unsigned short* vbb = vtile(s + 4);
      const bf16x8 kfa = loadK(s);
      const u16x4 va0 = *(const u16x4*)(vba);
      const u16x4 va1 = *(const u16x4*)(vba + 8);
      const u16x4 va2 = *(const u16x4*)(vba + 16);
      const u16x4 va3 = *(const u16x4*)(vba + 24);
      const bf16x8 kfb = loadK(s + 4);
      const u16x4 vb0 = *(const u16x4*)(vbb);
      const u16x4 vb1 = *(const u16x4*)(vbb + 8);
      const u16x4 vb2 = *(const u16x4*)(vbb + 16);
      const u16x4 vb3 = *(const u16x4*)(vbb + 24);

      f32x16 sa = {}, sb = {};
      __builtin_amdgcn_s_setprio(1);
      sa = __builtin_amdgcn_mfma_f32_32x32x16_bf16(kfa, qf, sa, 0, 0, 0);
      sb = __builtin_amdgcn_mfma_f32_32x32x16_bf16(kfb, qf, sb, 0, 0, 0);
      __builtin_amdgcn_s_setprio(0);

      if (s == tile) mask_diag(sa, s * 32);
      if (s + 4 == tile) mask_diag(sb, (s + 4) * 32);

      rescale_if(fmaxf(lmax16(sa), lmax16(sb)));
      expsum(sa);
      expsum(sb);
      pv(sa, va0, va1, va2, va3);
      pv(sb, vb0, vb1, vb2, vb3);
    }
    if (s < ns) {                       // leftover single step
      const unsigned short* vba = vtile(s);
      const bf16x8 kfa = loadK(s);
      const u16x4 va0 = *(const u16x4*)(vba);
      const u16x4 va1 = *(const u16x4*)(vba + 8);
      const u16x4 va2 = *(const u16x4*)(vba + 16);
      const u16x4 va3 = *(const u16x4*)(vba + 24);
      f32x16 sa = {};
      __builtin_amdgcn_s_setprio(1);
      sa = __builtin_amdgcn_mfma_f32_32x32x16_bf16(kfa, qf, sa, 0, 0, 0);
      __builtin_amdgcn_s_setprio(0);
      if (s == tile) mask_diag(sa, s * 32);
      rescale_if(lmax16(sa));
      expsum(sa);
      pv(sa, va0, va1, va2, va3);
    }

    lsum += __shfl_xor(lsum, 32, 64);   // lane pair holds same q
    Pm[slot][w][lane31] = m;
    Pl[slot][w][lane31] = lsum;
#pragma unroll
    for (int j = 0; j < 8; ++j) {
      const int dj = (j & 3) + 8 * (j >> 2) + 4 * h;
      Po[slot][w][lane31][dj] = acc[j];
    }
  };

  // phase A: steps i = w, w+4, ... while i < nsA
  run_phase(tileA, w, nsA, 0);
  // phase B: continue combined list; first B step = i_end - nsA
  const int cA = (nsA - w + 3) >> 2;
  const int sB0 = w + 4 * cA - nsA;
  run_phase(tileB, sB0, nsB, 1);

  __syncthreads();

  if (w < 2) {                          // wave 0 -> tile A, wave 1 -> tile B
    const int tile = (w == 0) ? tileA : tileB;
    const int qidx = tile * 32 + lane31;
    float M = Pm[w][0][lane31];
#pragma unroll
    for (int p = 1; p < 4; ++p) M = fmaxf(M, Pm[w][p][lane31]);
    float L = 0.f, od[8] = {};
#pragma unroll
    for (int p = 0; p < 4; ++p) {
      const float wsc = EXP2F(Pm[w][p][lane31] - M);  // empty slots -> 0
      L = fmaf(Pl[w][p][lane31], wsc, L);
#pragma unroll
      for (int j = 0; j < 8; ++j) {
        const int dj = (j & 3) + 8 * (j >> 2) + 4 * h;
        od[j] = fmaf(Po[w][p][lane31][dj], wsc, od[j]);
      }
    }
    const float inv = 1.f / L;
    float* base = att + ((size_t)bh * T + qidx) * D;
    *(float4*)(base + 4 * h) =
        make_float4(od[0] * inv, od[1] * inv, od[2] * inv, od[3] * inv);
    *(float4*)(base + 8 + 4 * h) =
        make_float4(od[4] * inv, od[5] * inv, od[6] * inv, od[7] * inv);
  }
}

// ---------------------------------------------------------------------------
// Kernel 3: output projection + bias (fp32, unchanged).
// ---------------------------------------------------------------------------
__global__ __launch_bounds__(256) void out_proj(
    const float* __restrict__ att, const float* __restrict__ Wp,
    const float* __restrict__ bp, float* __restrict__ out) {
  __shared__ float As[128][68];
  __shared__ float Bs[128][68];
  const int tid = threadIdx.x;
  const int t0 = blockIdx.x * 64;
  const int c0 = blockIdx.y * 64;

  for (int f = tid; f < 2048; f += 256) {
    const int mm = f & 63;
    const int cp = (f >> 6) << 2;
    const int tr = t0 + mm;
    const int b = tr >> 12, t = tr & (T - 1);
    const int h = cp >> 4, d0 = cp & 15;
    const float4 v = *(const float4*)(att + (((size_t)b * H + h) * T + t) * D + d0);
    As[cp + 0][mm] = v.x; As[cp + 1][mm] = v.y; As[cp + 2][mm] = v.z; As[cp + 3][mm] = v.w;
  }
  const float4* wsrc = (const float4*)(Wp + (size_t)c0 * C);
  for (int f = tid; f < 2048; f += 256) {
    const float4 v = wsrc[f];
    const int n = f >> 5, k = (f & 31) << 2;
    Bs[k + 0][n] = v.x; Bs[k + 1][n] = v.y; Bs[k + 2][n] = v.z; Bs[k + 3][n] = v.w;
  }
  __syncthreads();

  const int tx = tid & 15, ty = tid >> 4;
  float acc[4][4] = {};
#pragma unroll 8
  for (int k = 0; k < 128; ++k) {
    const float4 a = *(const float4*)&As[k][ty * 4];
    const float4 b = *(const float4*)&Bs[k][tx * 4];
    const float av[4] = {a.x, a.y, a.z, a.w};
    const float bv[4] = {b.x, b.y, b.z, b.w};
#pragma unroll
    for (int i = 0; i < 4; ++i)
#pragma unroll
      for (int j = 0; j < 4; ++j) acc[i][j] = fmaf(av[i], bv[j], acc[i][j]);
  }

  const float4 bias = *(const float4*)(bp + c0 + tx * 4);
#pragma unroll
  for (int i = 0; i < 4; ++i) {
    const int tr = t0 + ty * 4 + i;
    const float4 v = make_float4(acc[i][0] + bias.x, acc[i][1] + bias.y,
                                 acc[i][2] + bias.z, acc[i][3] + bias.w);
    *(float4*)(out + (size_t)tr * C + c0 + tx * 4) = v;
  }
}

}  // namespace

extern "C" void kernel_launch(void* const* d_in, const int* in_sizes, int n_in,
                              void* d_out, int out_size, void* d_ws, size_t ws_size,
                              hipStream_t stream) {
  // setup_inputs order: x, Wk, Wq, Wv, Wp, bp
  const float* x  = (const float*)d_in[0];
  const float* Wk = (const float*)d_in[1];
  const float* Wq = (const float*)d_in[2];
  const float* Wv = (const float*)d_in[3];
  const float* Wp = (const float*)d_in[4];
  const float* bp = (const float*)d_in[5];

  float* att = (float*)d_ws;                             // 4 MiB fp32
  unsigned short* Qbf = (unsigned short*)(att + PLANE);  // 2 MiB bf16
  unsigned short* Kbf = Qbf + PLANE;                     // 2 MiB
  unsigned short* Vtb = Kbf + PLANE;                     // 2 MiB (10 MiB ws)

  qkv_proj<<<dim3(128, 6), 256, 0, stream>>>(x, Wq, Wk, Wv, Qbf, Kbf, Vtb);
  attn_fwd<<<dim3(1024), 256, 0, stream>>>(Qbf, Kbf, Vtb, att);
  out_proj<<<dim3(128, 2), 256, 0, stream>>>(att, Wp, bp, (float*)d_out);
}